// Round 1
// 240.155 us; speedup vs baseline: 1.0280x; 1.0280x over previous
//
#include <hip/hip_runtime.h>
#include <math.h>

#define B_   2
#define P_   200000
#define Q_   100
#define NREP 64          // bitmask replicas per batch (decontend atomics)

// ws byte layout:
//   [0, 2048)      unsigned long long flags[B_][NREP][2]  (zeroed by prep)
//   [2048, 2848)   float msc[B_*Q_]                        (written by prep)
//
// d_out (float): [0,B*P) sem | [B*P,2BP) ins | [2BP,3BP) max_confs
// pass1 stashes mid (float, -1 invalid) in ins slot; pass23 finalizes.

// Single tiny block: zero the 2KB flag table AND compute per-query msc.
__global__ void pano_prep(const float* __restrict__ logits,
                          float* __restrict__ msc,
                          unsigned int* __restrict__ flags32)
{
    const int tid = threadIdx.x;
    flags32[tid]       = 0u;      // 512 u32 words total
    flags32[tid + 256] = 0u;
    if (tid < B_ * Q_) {
        float l0 = logits[tid * 2 + 0];
        float l1 = logits[tid * 2 + 1];
        // keep iff argmax==0 iff !(l1>l0) (jnp first-index tie rule)
        msc[tid] = (l1 > l0) ? -1e30f : fmaxf(l0, l1);
    }
}

// 4 lanes/row, 16 rows/wave, 64 rows per 256-thread block. P_ = 3125*64.
__global__ __launch_bounds__(256) void pano_pass1(
    const float* __restrict__ masks,         // [B,P,Q]
    const unsigned char* __restrict__ pad,   // [B,P]
    float* __restrict__ out,                 // [3,B,P]
    const float* __restrict__ msc,           // [B,Q] ws
    unsigned long long* __restrict__ flags)  // [B][NREP][2] ws
{
    const int b = blockIdx.y, tid = threadIdx.x;
    __shared__ float s_msc[Q_];
    __shared__ int   s_flag[Q_];
    if (tid < Q_) { s_msc[tid] = msc[b * Q_ + tid]; s_flag[tid] = 0; }
    __syncthreads();

    const int wave = tid >> 6, wl = tid & 63;
    const int g = wl >> 2, l = wl & 3;
    const int p = blockIdx.x * 64 + wave * 16 + g;

    const float* rowp = masks + ((size_t)b * P_ + p) * Q_;
    const float4* grow = reinterpret_cast<const float4*>(rowp);

    // 7 independent 16B loads per lane -> high MLP
    float4 v[7];
    #pragma unroll
    for (int k = 0; k < 6; ++k) v[k] = grow[k * 4 + l];
    v[6] = grow[24];                 // same addr all 4 lanes; only l==0 consumes

    float S0 = 0.0f;
    float v1 = -INFINITY, v2 = -INFINITY, m1 = 0.0f;
    int   q1 = -1;

    #pragma unroll
    for (int k = 0; k < 7; ++k) {
        const bool act = (k < 6) || (l == 0);
        const int  qb  = (k < 6) ? (16 * k + 4 * l) : 96;
        float xv[4] = {v[k].x, v[k].y, v[k].z, v[k].w};
        #pragma unroll
        for (int e = 0; e < 4; ++e) {
            int q = qb + e;
            // FAST path: v_exp + v_rcp sigmoid (error ~1e-6 rel)
            float m   = __builtin_amdgcn_rcpf(1.0f + __expf(-xv[e]));
            float val = act ? s_msc[q] * m : -INFINITY;  // ghost: exp->0, never wins
            S0 += __expf(val);                           // vals bounded ~[0,4]
            bool t = val > v1;                           // strict: first-max tie
            v2 = t ? v1 : fmaxf(v2, val);
            v1 = t ? val : v1;
            m1 = t ? m   : m1;
            q1 = t ? q   : q1;
        }
    }

    // merge 4 lanes (xor 1,2); v1 tie -> smaller q (unsigned: -1 loses)
    #pragma unroll
    for (int off = 1; off <= 2; off <<= 1) {
        float So  = __shfl_xor(S0, off, 64);
        float v1o = __shfl_xor(v1, off, 64);
        float v2o = __shfl_xor(v2, off, 64);
        float m1o = __shfl_xor(m1, off, 64);
        int   q1o = __shfl_xor(q1, off, 64);
        S0 += So;
        bool t = (v1o > v1) || (v1o == v1 && (unsigned)q1o < (unsigned)q1);
        v2 = fmaxf(fminf(v1, v1o), fmaxf(v2, v2o));      // 2nd max of union
        v1 = t ? v1o : v1;
        m1 = t ? m1o : m1;
        q1 = t ? q1o : q1;
    }

    // EXACT fallback when fast top-2 gap can't certify argmax (~0.06% rows):
    // bit-identical chain to the validated R2 kernel (expf + IEEE div).
    if (l == 0 && (v1 - v2) < 5e-5f) {
        float bv = -INFINITY, bm = 0.0f; int bq = -1;
        for (int q = 0; q < Q_; ++q) {
            float x = rowp[q];                 // L1-hot
            float e = expf(-x);
            float m = 1.0f / (1.0f + e);
            float vv = s_msc[q] * m;
            if (vv > bv) { bv = vv; bq = q; bm = m; }
        }
        q1 = bq; m1 = bm;                      // v1/S0 keep fast values (2% tol)
    }

    bool valid = (q1 >= 0) && (s_msc[q1] > -1e29f) &&     // keep[mid]
                 (m1 >= 1e-3f) &&
                 (pad[(size_t)b * P_ + p] == 0);

    float conf = __expf(v1) * __builtin_amdgcn_rcpf(S0);  // 2% tol
    float insf = valid ? (float)q1 : -1.0f;
    if (l == 0 && valid) s_flag[q1] = 1;                  // benign race

    // compact stores: lane t<16 gathers row t's result from its leader lane 4t
    int   src    = (wl & 15) * 4;
    float conf_g = __shfl(conf, src, 64);
    float insf_g = __shfl(insf, src, 64);
    if (wl < 16) {
        int prow = blockIdx.x * 64 + wave * 16 + wl;
        size_t o = (size_t)b * P_ + prow;
        out[o]                       = 0.0f;   // sem: labels[mid]==0 whenever valid
        out[(size_t)B_ * P_ + o]     = insf_g;
        out[2 * (size_t)B_ * P_ + o] = conf_g;
    }

    __syncthreads();
    // ballot the per-block flag table into two 64-bit masks; <=2 atomics/block
    if (wave < 2) {
        bool pred = (tid < Q_) && (s_flag[tid] != 0);   // wave w: bit wl == q tid
        unsigned long long mbits = __ballot(pred);
        if (wl == 0 && mbits) {
            int rep = blockIdx.x & (NREP - 1);
            atomicOr(&flags[((size_t)b * NREP + rep) * 2 + wave], mbits);
        }
    }
}

// fused: OR-reduce flag replicas (L2-hot, 1KB/block) + cumsum + ins fixup
__global__ __launch_bounds__(256) void pano_pass23(
    const unsigned int* __restrict__ flags32,   // [B][NREP*4] u32 view
    float* __restrict__ out)
{
    const int b = blockIdx.y, tid = threadIdx.x;
    __shared__ unsigned int s_bits[4];
    __shared__ int s_seg[Q_];
    if (tid < 4) s_bits[tid] = 0u;
    __syncthreads();
    unsigned int w = flags32[b * 256 + tid];    // word tid&3 of replica tid>>2
    if (w) atomicOr(&s_bits[tid & 3], w);
    __syncthreads();
    if (tid == 0) {
        int c = 0;
        #pragma unroll
        for (int q = 0; q < Q_; ++q) {
            c += (s_bits[q >> 5] >> (q & 31)) & 1;
            s_seg[q] = c;
        }
    }
    __syncthreads();

    int p = blockIdx.x * 256 + tid;
    if (p < P_) {
        size_t o = (size_t)B_ * P_ + (size_t)b * P_ + p;
        float f = out[o];
        out[o] = (f >= 0.0f) ? (float)s_seg[(int)f] : 0.0f;
    }
}

extern "C" void kernel_launch(void* const* d_in, const int* in_sizes, int n_in,
                              void* d_out, int out_size, void* d_ws, size_t ws_size,
                              hipStream_t stream) {
    const float* logits = (const float*)d_in[0];
    const float* masks  = (const float*)d_in[1];
    const unsigned char* pad = (const unsigned char*)d_in[2];
    float* out = (float*)d_out;

    unsigned long long* flags   = (unsigned long long*)d_ws;  // [B][NREP][2]
    unsigned int*       flags32 = (unsigned int*)d_ws;        // same, u32 view
    float*              mscp    = (float*)((char*)d_ws + 2048);

    pano_prep<<<dim3(1), dim3(256), 0, stream>>>(logits, mscp, flags32);
    pano_pass1<<<dim3(P_ / 64, B_), dim3(256), 0, stream>>>(masks, pad, out, mscp, flags);
    pano_pass23<<<dim3((P_ + 255) / 256, B_), dim3(256), 0, stream>>>(flags32, out);
}